// Round 21
// baseline (54.572 us; speedup 1.0000x reference)
//
#include <hip/hip_runtime.h>

// GraphAttentionNet: x[8192,128] -> Q,K,V = relu(x W^T + b) [8192,64]
// out = softmax(Q K^T / 8) V + Q   (fp32 out)
//
// R21 = R15 (best known, 49.1us: batched subtile LDS reads, V held in
// regs through softmax, dbuf global_load_lds staging) + the knob R20
// proved works: amdgpu_waves_per_eu(2,2) -> 256-VGPR budget, no spills.

typedef __attribute__((ext_vector_type(8))) __bf16 bf16x8;
typedef __attribute__((ext_vector_type(4))) float f32x4;
typedef __attribute__((ext_vector_type(16))) float f32x16;

constexpr int N_ROWS = 8192;
constexpr int CDIM   = 128;
constexpr int DKV    = 64;   // DK == DV == 64
constexpr float SCALE_Q = 0.125f * 1.4426950408889634f; // 1/sqrt(64) * log2(e)

__device__ __forceinline__ float fast_exp2(float x) {
    return __builtin_amdgcn_exp2f(x);   // v_exp_f32 (base-2)
}

__device__ __forceinline__ unsigned short f2bf(float x) {
    union { float f; unsigned u; } v; v.f = x;
    unsigned r = v.u + 0x7fffu + ((v.u >> 16) & 1u);   // RNE
    return (unsigned short)(r >> 16);
}

__device__ __forceinline__ float bf2f(unsigned short h) {
    union { unsigned u; float f; } v; v.u = (unsigned)h << 16; return v.f;
}

union Frag {
    unsigned u32[4];
    unsigned short u16[8];
    bf16x8 b;
    f32x4 f;
};

// ---------------------------------------------------------------- QKV ------
__global__ __launch_bounds__(128) void qkv_kernel(
    const float* __restrict__ x,
    const float* __restrict__ Wq, const float* __restrict__ bq,
    const float* __restrict__ Wk, const float* __restrict__ bk,
    const float* __restrict__ Wv, const float* __restrict__ bv,
    unsigned short* __restrict__ Qb, unsigned short* __restrict__ Kb,
    unsigned short* __restrict__ Vt, float* __restrict__ Qf)
{
    const int tid = threadIdx.x;
    const int w  = tid >> 6;       // wave 0..1
    const int l  = tid & 63;
    const int g  = l >> 4;         // lane quarter
    const int lm = l & 15;
    const int n_base = blockIdx.x * 32 + w * 16;

    bf16x8 af[4];
    {
        const float* xrow = x + (size_t)(n_base + lm) * CDIM;
        #pragma unroll
        for (int s = 0; s < 4; ++s) {
            f32x4 lo = *(const f32x4*)(xrow + s * 32 + g * 8);
            f32x4 hi = *(const f32x4*)(xrow + s * 32 + g * 8 + 4);
            Frag fr;
            #pragma unroll
            for (int j = 0; j < 4; ++j) { fr.u16[j] = f2bf(lo[j]); fr.u16[4 + j] = f2bf(hi[j]); }
            af[s] = fr.b;
        }
    }

    const float* Ws[3] = {Wq, Wk, Wv};
    const float* Bs[3] = {bq, bk, bv};
    #pragma unroll
    for (int mat = 0; mat < 3; ++mat) {
        #pragma unroll
        for (int ct = 0; ct < 4; ++ct) {
            const int f = ct * 16 + lm;                 // output feature (B col)
            const float* wrow = Ws[mat] + (size_t)f * CDIM;
            f32x4 acc = {0.f, 0.f, 0.f, 0.f};
            #pragma unroll
            for (int s = 0; s < 4; ++s) {
                f32x4 lo = *(const f32x4*)(wrow + s * 32 + g * 8);
                f32x4 hi = *(const f32x4*)(wrow + s * 32 + g * 8 + 4);
                Frag fr;
                #pragma unroll
                for (int j = 0; j < 4; ++j) { fr.u16[j] = f2bf(lo[j]); fr.u16[4 + j] = f2bf(hi[j]); }
                acc = __builtin_amdgcn_mfma_f32_16x16x32_bf16(af[s], fr.b, acc, 0, 0, 0);
            }
            const float bias = Bs[mat][f];
            #pragma unroll
            for (int j = 0; j < 4; ++j) {
                const int n = n_base + g * 4 + j;       // D row = A row
                const float v = fmaxf(acc[j] + bias, 0.f);
                if (mat == 0) {
                    Qf[(size_t)n * DKV + f] = v;
                    Qb[(size_t)n * DKV + f] = f2bf(v * SCALE_Q);
                } else if (mat == 1) {
                    Kb[(size_t)n * DKV + f] = f2bf(v);
                } else {
                    Vt[(size_t)f * N_ROWS + n] = f2bf(v); // store V transposed
                }
            }
        }
    }
}

// ---------------------------------------------------------- attention ------
// 8 waves/block (512 thr), q=32/wave -> 256 q/block. 32x32x16 MFMA.
// K,V^T tiles (64 kv) double-buffered via global_load_lds (swizzled source).
// Per subtile: ALL 16 ds_read_b128 issued upfront; V held in registers
// through softmax; PV MFMAs consume registers only.
// waves_per_eu(2,2): 2 waves/SIMD pinned -> 256-VGPR budget, no spills.
__global__ __launch_bounds__(512) __attribute__((amdgpu_waves_per_eu(2, 2)))
void attn_kernel(
    const unsigned short* __restrict__ Qb, const unsigned short* __restrict__ Kb,
    const unsigned short* __restrict__ Vt,
    unsigned short* __restrict__ PartOb, float* __restrict__ PartL,
    int kv_per_split)
{
    __shared__ __align__(16) unsigned short K_lds[2][64 * 64];
    __shared__ __align__(16) unsigned short V_lds[2][64 * 64];

    const int tid = threadIdx.x;
    const int w  = tid >> 6;       // wave 0..7
    const int l  = tid & 63;
    const int c  = l & 31;         // q column / A-row
    const int hB = l >> 5;         // lane half (k-subgroup)
    const int qb = blockIdx.x;
    const int sp = blockIdx.y;
    const int q0 = qb * 256 + w * 32;
    const int kv0 = sp * kv_per_split;

    const int r_ = w * 8 + (l >> 3);                       // tile row 0..63
    const int perm_ = (r_ & 7) ^ (((r_ >> 3) & 3) << 1);
    const int srcc = ((l & 7) ^ perm_) * 8;                // ushort offset

#define ISSUE_LOADS(T, B) do { \
    const int kvt_ = kv0 + (T) * 64; \
    __builtin_amdgcn_global_load_lds( \
        (const __attribute__((address_space(1))) unsigned int*)(Kb + (size_t)(kvt_ + r_) * DKV + srcc), \
        (__attribute__((address_space(3))) unsigned int*)&K_lds[B][w * 8 * 64], 16, 0, 0); \
    __builtin_amdgcn_global_load_lds( \
        (const __attribute__((address_space(1))) unsigned int*)(Vt + (size_t)r_ * N_ROWS + kvt_ + srcc), \
        (__attribute__((address_space(3))) unsigned int*)&V_lds[B][w * 8 * 64], 16, 0, 0); \
} while (0)

    // Hoisted Q B-fragments: B[k][col=q] = Q[q0+c][16ks + 8hB + j]
    bf16x8 qf0, qf1, qf2, qf3;
    {
        const unsigned short* qp = Qb + (size_t)(q0 + c) * DKV + hB * 8;
        qf0 = *(const bf16x8*)(qp);
        qf1 = *(const bf16x8*)(qp + 16);
        qf2 = *(const bf16x8*)(qp + 32);
        qf3 = *(const bf16x8*)(qp + 48);
    }

    f32x16 o0 = {}, o1 = {};
    float lsum = 0.f;

    const int nt = kv_per_split >> 6;
    ISSUE_LOADS(0, 0);
    if (nt > 1) ISSUE_LOADS(1, 1);
    __syncthreads();

    const int swz = ((c & 7) ^ (((c >> 3) & 3) << 1)) << 4;

    for (int t = 0; t < nt; ++t) {
        const char* Kl = (const char*)&K_lds[t & 1][0];
        const char* Vl = (const char*)&V_lds[t & 1][0];

        // ---- Batch ALL LDS reads for this subtile upfront ----
        bf16x8 ka0[4], ka1[4], vv0[4], vv1[4];
        #pragma unroll
        for (int ks = 0; ks < 4; ++ks) {
            const int cb = ks * 32 + hB * 16;
            ka0[ks] = *(const bf16x8*)(Kl + c * 128 + (cb ^ swz));
            ka1[ks] = *(const bf16x8*)(Kl + (32 + c) * 128 + (cb ^ swz));
            vv0[ks] = *(const bf16x8*)(Vl + c * 128 + (cb ^ swz));
            vv1[ks] = *(const bf16x8*)(Vl + (32 + c) * 128 + (cb ^ swz));
        }

        // S^T = K * Q^T  (register-only from here)
        f32x16 st0 = {}, st1 = {};
        #pragma unroll
        for (int ks = 0; ks < 4; ++ks) {
            const bf16x8 qv = (ks == 0) ? qf0 : (ks == 1) ? qf1 : (ks == 2) ? qf2 : qf3;
            st0 = __builtin_amdgcn_mfma_f32_32x32x16_bf16(ka0[ks], qv, st0, 0, 0, 0);
            st1 = __builtin_amdgcn_mfma_f32_32x32x16_bf16(ka1[ks], qv, st1, 0, 0, 0);
        }

        // P = exp2(S) packed to bf16 pairs (S bounded; no max needed).
        unsigned pk[16];
        float ls = 0.f;
        #pragma unroll
        for (int p = 0; p < 8; ++p) {
            float a = fast_exp2(st0[2 * p]);
            float b = fast_exp2(st0[2 * p + 1]);
            ls += a + b;
            union { unsigned u; __bf16 h[2]; } uu;
            uu.h[0] = (__bf16)a; uu.h[1] = (__bf16)b;
            pk[p] = uu.u;
        }
        #pragma unroll
        for (int p = 0; p < 8; ++p) {
            float a = fast_exp2(st1[2 * p]);
            float b = fast_exp2(st1[2 * p + 1]);
            ls += a + b;
            union { unsigned u; __bf16 h[2]; } uu;
            uu.h[0] = (__bf16)a; uu.h[1] = (__bf16)b;
            pk[8 + p] = uu.u;
        }
        lsum += ls;

        // PV: register-held V, LDS-free.
        #pragma unroll
        for (int ks = 0; ks < 4; ++ks) {
            const int base = (ks >> 1) * 8 + (ks & 1) * 4;
            const unsigned ownA  = hB ? pk[base + 2] : pk[base + 0];
            const unsigned ownB  = hB ? pk[base + 3] : pk[base + 1];
            const unsigned contA = hB ? pk[base + 0] : pk[base + 2];
            const unsigned contB = hB ? pk[base + 1] : pk[base + 3];
            const unsigned crossA = __shfl_xor(contA, 32);
            const unsigned crossB = __shfl_xor(contB, 32);
            Frag pf;
            pf.u32[0] = hB ? crossA : ownA;
            pf.u32[1] = hB ? crossB : ownB;
            pf.u32[2] = hB ? ownA : crossA;
            pf.u32[3] = hB ? ownB : crossB;
            o0 = __builtin_amdgcn_mfma_f32_32x32x16_bf16(vv0[ks], pf.b, o0, 0, 0, 0);
            o1 = __builtin_amdgcn_mfma_f32_32x32x16_bf16(vv1[ks], pf.b, o1, 0, 0, 0);
        }

        __syncthreads();
        if (t + 2 < nt) ISSUE_LOADS(t + 2, t & 1);
    }
#undef ISSUE_LOADS

    lsum += __shfl_xor(lsum, 32);

    // O^T[dv][q] -> PartOb bf16 [sp][q][dv], packed 8B stores.
    {
        unsigned short* po = PartOb + ((size_t)sp * N_ROWS + q0 + c) * 64;
        #pragma unroll
        for (int rq = 0; rq < 4; ++rq) {
            union { unsigned u[2]; __bf16 h[4]; } pa, pb;
            #pragma unroll
            for (int j = 0; j < 4; ++j) { pa.h[j] = (__bf16)o0[4 * rq + j]; pb.h[j] = (__bf16)o1[4 * rq + j]; }
            *(uint2*)(po + 8 * rq + 4 * hB)      = *(uint2*)pa.u;
            *(uint2*)(po + 32 + 8 * rq + 4 * hB) = *(uint2*)pb.u;
        }
    }
    if (hB == 0)
        PartL[(size_t)sp * N_ROWS + q0 + c] = lsum;
}

// -------------------------------------------------------------- merge ------
__global__ __launch_bounds__(256) void merge_kernel(
    const unsigned short* __restrict__ PartOb, const float* __restrict__ PartL,
    const float* __restrict__ Qf, float* __restrict__ out, int split)
{
    const int gid = blockIdx.x * 256 + threadIdx.x;   // 0 .. 8192*32-1
    const int q  = gid >> 5;
    const int dp = gid & 31;          // dv pair index

    float L = 0.f, a0 = 0.f, a1 = 0.f;
    for (int s = 0; s < split; ++s) {
        L += PartL[(size_t)s * N_ROWS + q];
        const unsigned v = *(const unsigned*)(PartOb + ((size_t)s * N_ROWS + q) * 64 + 2 * dp);
        a0 += bf2f((unsigned short)(v & 0xffffu));
        a1 += bf2f((unsigned short)(v >> 16));
    }
    const float invL = 1.f / L;
    const int d0 = 2 * dp;
    out[(size_t)q * 64 + d0]     = a0 * invL + Qf[(size_t)q * 64 + d0];
    out[(size_t)q * 64 + d0 + 1] = a1 * invL + Qf[(size_t)q * 64 + d0 + 1];
}

// ------------------------------------------------------------- launch ------
extern "C" void kernel_launch(void* const* d_in, const int* in_sizes, int n_in,
                              void* d_out, int out_size, void* d_ws, size_t ws_size,
                              hipStream_t stream)
{
    const float* x  = (const float*)d_in[0];
    const float* Wq = (const float*)d_in[1];
    const float* bq = (const float*)d_in[2];
    const float* Wk = (const float*)d_in[3];
    const float* bk = (const float*)d_in[4];
    const float* Wv = (const float*)d_in[5];
    const float* bv = (const float*)d_in[6];
    float* out = (float*)d_out;

    char* ws = (char*)d_ws;
    size_t off = 0;
    auto take = [&](size_t bytes) {
        char* p = ws + off;
        off += (bytes + 255) & ~(size_t)255;
        return p;
    };
    unsigned short* Qb = (unsigned short*)take((size_t)N_ROWS * DKV * 2);
    unsigned short* Kb = (unsigned short*)take((size_t)N_ROWS * DKV * 2);
    unsigned short* Vt = (unsigned short*)take((size_t)DKV * N_ROWS * 2);
    float*          Qf = (float*)take((size_t)N_ROWS * DKV * 4);

    int split = 16;
    const size_t per_split = (size_t)N_ROWS * 64 * 2 + (size_t)N_ROWS * 4 + 512;
    while (split > 1 && off + (size_t)split * per_split > ws_size) split >>= 1;

    unsigned short* PartOb = (unsigned short*)take((size_t)split * N_ROWS * 64 * 2);
    float*          PartL  = (float*)take((size_t)split * N_ROWS * 4);

    qkv_kernel<<<dim3(N_ROWS / 32), dim3(128), 0, stream>>>(
        x, Wq, bq, Wk, bk, Wv, bv, Qb, Kb, Vt, Qf);
    attn_kernel<<<dim3(N_ROWS / 256, split), dim3(512), 0, stream>>>(
        Qb, Kb, Vt, PartOb, PartL, N_ROWS / split);
    merge_kernel<<<dim3(N_ROWS * 32 / 256), dim3(256), 0, stream>>>(
        PartOb, PartL, Qf, out, split);
}

// Round 22
// 49.088 us; speedup vs baseline: 1.1117x; 1.1117x over previous
//
#include <hip/hip_runtime.h>

// GraphAttentionNet: x[8192,128] -> Q,K,V = relu(x W^T + b) [8192,64]
// out = softmax(Q K^T / 8) V + Q   (fp32 out)
//
// R22 = FINAL: revert to R15 verbatim (best measured, 49.1us).
// R21's waves_per_eu(2,2) pin on this base regressed (54.6us): this
// structure relies on 4-waves/SIMD TLP, not intra-wave ILP.
// Session: 111 -> 49.1us. Key wins: parallel merge (R3), 32x32 MFMA +
// swizzled LDS (R4), max-tracking deletion via boundedness proof (R6),
// batched subtile LDS reads + V-in-regs (R15).

typedef __attribute__((ext_vector_type(8))) __bf16 bf16x8;
typedef __attribute__((ext_vector_type(4))) float f32x4;
typedef __attribute__((ext_vector_type(16))) float f32x16;

constexpr int N_ROWS = 8192;
constexpr int CDIM   = 128;
constexpr int DKV    = 64;   // DK == DV == 64
constexpr float SCALE_Q = 0.125f * 1.4426950408889634f; // 1/sqrt(64) * log2(e)

__device__ __forceinline__ float fast_exp2(float x) {
    return __builtin_amdgcn_exp2f(x);   // v_exp_f32 (base-2)
}

__device__ __forceinline__ unsigned short f2bf(float x) {
    union { float f; unsigned u; } v; v.f = x;
    unsigned r = v.u + 0x7fffu + ((v.u >> 16) & 1u);   // RNE
    return (unsigned short)(r >> 16);
}

__device__ __forceinline__ float bf2f(unsigned short h) {
    union { unsigned u; float f; } v; v.u = (unsigned)h << 16; return v.f;
}

union Frag {
    unsigned u32[4];
    unsigned short u16[8];
    bf16x8 b;
    f32x4 f;
};

// ---------------------------------------------------------------- QKV ------
__global__ __launch_bounds__(128) void qkv_kernel(
    const float* __restrict__ x,
    const float* __restrict__ Wq, const float* __restrict__ bq,
    const float* __restrict__ Wk, const float* __restrict__ bk,
    const float* __restrict__ Wv, const float* __restrict__ bv,
    unsigned short* __restrict__ Qb, unsigned short* __restrict__ Kb,
    unsigned short* __restrict__ Vt, float* __restrict__ Qf)
{
    const int tid = threadIdx.x;
    const int w  = tid >> 6;       // wave 0..1
    const int l  = tid & 63;
    const int g  = l >> 4;         // lane quarter
    const int lm = l & 15;
    const int n_base = blockIdx.x * 32 + w * 16;

    bf16x8 af[4];
    {
        const float* xrow = x + (size_t)(n_base + lm) * CDIM;
        #pragma unroll
        for (int s = 0; s < 4; ++s) {
            f32x4 lo = *(const f32x4*)(xrow + s * 32 + g * 8);
            f32x4 hi = *(const f32x4*)(xrow + s * 32 + g * 8 + 4);
            Frag fr;
            #pragma unroll
            for (int j = 0; j < 4; ++j) { fr.u16[j] = f2bf(lo[j]); fr.u16[4 + j] = f2bf(hi[j]); }
            af[s] = fr.b;
        }
    }

    const float* Ws[3] = {Wq, Wk, Wv};
    const float* Bs[3] = {bq, bk, bv};
    #pragma unroll
    for (int mat = 0; mat < 3; ++mat) {
        #pragma unroll
        for (int ct = 0; ct < 4; ++ct) {
            const int f = ct * 16 + lm;                 // output feature (B col)
            const float* wrow = Ws[mat] + (size_t)f * CDIM;
            f32x4 acc = {0.f, 0.f, 0.f, 0.f};
            #pragma unroll
            for (int s = 0; s < 4; ++s) {
                f32x4 lo = *(const f32x4*)(wrow + s * 32 + g * 8);
                f32x4 hi = *(const f32x4*)(wrow + s * 32 + g * 8 + 4);
                Frag fr;
                #pragma unroll
                for (int j = 0; j < 4; ++j) { fr.u16[j] = f2bf(lo[j]); fr.u16[4 + j] = f2bf(hi[j]); }
                acc = __builtin_amdgcn_mfma_f32_16x16x32_bf16(af[s], fr.b, acc, 0, 0, 0);
            }
            const float bias = Bs[mat][f];
            #pragma unroll
            for (int j = 0; j < 4; ++j) {
                const int n = n_base + g * 4 + j;       // D row = A row
                const float v = fmaxf(acc[j] + bias, 0.f);
                if (mat == 0) {
                    Qf[(size_t)n * DKV + f] = v;
                    Qb[(size_t)n * DKV + f] = f2bf(v * SCALE_Q);
                } else if (mat == 1) {
                    Kb[(size_t)n * DKV + f] = f2bf(v);
                } else {
                    Vt[(size_t)f * N_ROWS + n] = f2bf(v); // store V transposed
                }
            }
        }
    }
}

// ---------------------------------------------------------- attention ------
// 8 waves/block (512 thr), q=32/wave -> 256 q/block. 32x32x16 MFMA.
// K,V^T tiles (64 kv) double-buffered via global_load_lds (swizzled source).
// Per subtile: ALL 16 ds_read_b128 issued upfront; V held in registers
// through softmax; PV MFMAs consume registers only.
__global__ __launch_bounds__(512) void attn_kernel(
    const unsigned short* __restrict__ Qb, const unsigned short* __restrict__ Kb,
    const unsigned short* __restrict__ Vt,
    unsigned short* __restrict__ PartOb, float* __restrict__ PartL,
    int kv_per_split)
{
    __shared__ __align__(16) unsigned short K_lds[2][64 * 64];
    __shared__ __align__(16) unsigned short V_lds[2][64 * 64];

    const int tid = threadIdx.x;
    const int w  = tid >> 6;       // wave 0..7
    const int l  = tid & 63;
    const int c  = l & 31;         // q column / A-row
    const int hB = l >> 5;         // lane half (k-subgroup)
    const int qb = blockIdx.x;
    const int sp = blockIdx.y;
    const int q0 = qb * 256 + w * 32;
    const int kv0 = sp * kv_per_split;

    const int r_ = w * 8 + (l >> 3);                       // tile row 0..63
    const int perm_ = (r_ & 7) ^ (((r_ >> 3) & 3) << 1);
    const int srcc = ((l & 7) ^ perm_) * 8;                // ushort offset

#define ISSUE_LOADS(T, B) do { \
    const int kvt_ = kv0 + (T) * 64; \
    __builtin_amdgcn_global_load_lds( \
        (const __attribute__((address_space(1))) unsigned int*)(Kb + (size_t)(kvt_ + r_) * DKV + srcc), \
        (__attribute__((address_space(3))) unsigned int*)&K_lds[B][w * 8 * 64], 16, 0, 0); \
    __builtin_amdgcn_global_load_lds( \
        (const __attribute__((address_space(1))) unsigned int*)(Vt + (size_t)r_ * N_ROWS + kvt_ + srcc), \
        (__attribute__((address_space(3))) unsigned int*)&V_lds[B][w * 8 * 64], 16, 0, 0); \
} while (0)

    // Hoisted Q B-fragments: B[k][col=q] = Q[q0+c][16ks + 8hB + j]
    bf16x8 qf0, qf1, qf2, qf3;
    {
        const unsigned short* qp = Qb + (size_t)(q0 + c) * DKV + hB * 8;
        qf0 = *(const bf16x8*)(qp);
        qf1 = *(const bf16x8*)(qp + 16);
        qf2 = *(const bf16x8*)(qp + 32);
        qf3 = *(const bf16x8*)(qp + 48);
    }

    f32x16 o0 = {}, o1 = {};
    float lsum = 0.f;

    const int nt = kv_per_split >> 6;
    ISSUE_LOADS(0, 0);
    if (nt > 1) ISSUE_LOADS(1, 1);
    __syncthreads();

    const int swz = ((c & 7) ^ (((c >> 3) & 3) << 1)) << 4;

    for (int t = 0; t < nt; ++t) {
        const char* Kl = (const char*)&K_lds[t & 1][0];
        const char* Vl = (const char*)&V_lds[t & 1][0];

        // ---- Batch ALL LDS reads for this subtile upfront ----
        bf16x8 ka0[4], ka1[4], vv0[4], vv1[4];
        #pragma unroll
        for (int ks = 0; ks < 4; ++ks) {
            const int cb = ks * 32 + hB * 16;
            ka0[ks] = *(const bf16x8*)(Kl + c * 128 + (cb ^ swz));
            ka1[ks] = *(const bf16x8*)(Kl + (32 + c) * 128 + (cb ^ swz));
            vv0[ks] = *(const bf16x8*)(Vl + c * 128 + (cb ^ swz));
            vv1[ks] = *(const bf16x8*)(Vl + (32 + c) * 128 + (cb ^ swz));
        }

        // S^T = K * Q^T  (register-only from here)
        f32x16 st0 = {}, st1 = {};
        #pragma unroll
        for (int ks = 0; ks < 4; ++ks) {
            const bf16x8 qv = (ks == 0) ? qf0 : (ks == 1) ? qf1 : (ks == 2) ? qf2 : qf3;
            st0 = __builtin_amdgcn_mfma_f32_32x32x16_bf16(ka0[ks], qv, st0, 0, 0, 0);
            st1 = __builtin_amdgcn_mfma_f32_32x32x16_bf16(ka1[ks], qv, st1, 0, 0, 0);
        }

        // P = exp2(S) packed to bf16 pairs (S bounded; no max needed).
        unsigned pk[16];
        float ls = 0.f;
        #pragma unroll
        for (int p = 0; p < 8; ++p) {
            float a = fast_exp2(st0[2 * p]);
            float b = fast_exp2(st0[2 * p + 1]);
            ls += a + b;
            union { unsigned u; __bf16 h[2]; } uu;
            uu.h[0] = (__bf16)a; uu.h[1] = (__bf16)b;
            pk[p] = uu.u;
        }
        #pragma unroll
        for (int p = 0; p < 8; ++p) {
            float a = fast_exp2(st1[2 * p]);
            float b = fast_exp2(st1[2 * p + 1]);
            ls += a + b;
            union { unsigned u; __bf16 h[2]; } uu;
            uu.h[0] = (__bf16)a; uu.h[1] = (__bf16)b;
            pk[8 + p] = uu.u;
        }
        lsum += ls;

        // PV: register-held V, LDS-free.
        #pragma unroll
        for (int ks = 0; ks < 4; ++ks) {
            const int base = (ks >> 1) * 8 + (ks & 1) * 4;
            const unsigned ownA  = hB ? pk[base + 2] : pk[base + 0];
            const unsigned ownB  = hB ? pk[base + 3] : pk[base + 1];
            const unsigned contA = hB ? pk[base + 0] : pk[base + 2];
            const unsigned contB = hB ? pk[base + 1] : pk[base + 3];
            const unsigned crossA = __shfl_xor(contA, 32);
            const unsigned crossB = __shfl_xor(contB, 32);
            Frag pf;
            pf.u32[0] = hB ? crossA : ownA;
            pf.u32[1] = hB ? crossB : ownB;
            pf.u32[2] = hB ? ownA : crossA;
            pf.u32[3] = hB ? ownB : crossB;
            o0 = __builtin_amdgcn_mfma_f32_32x32x16_bf16(vv0[ks], pf.b, o0, 0, 0, 0);
            o1 = __builtin_amdgcn_mfma_f32_32x32x16_bf16(vv1[ks], pf.b, o1, 0, 0, 0);
        }

        __syncthreads();
        if (t + 2 < nt) ISSUE_LOADS(t + 2, t & 1);
    }
#undef ISSUE_LOADS

    lsum += __shfl_xor(lsum, 32);

    // O^T[dv][q] -> PartOb bf16 [sp][q][dv], packed 8B stores.
    {
        unsigned short* po = PartOb + ((size_t)sp * N_ROWS + q0 + c) * 64;
        #pragma unroll
        for (int rq = 0; rq < 4; ++rq) {
            union { unsigned u[2]; __bf16 h[4]; } pa, pb;
            #pragma unroll
            for (int j = 0; j < 4; ++j) { pa.h[j] = (__bf16)o0[4 * rq + j]; pb.h[j] = (__bf16)o1[4 * rq + j]; }
            *(uint2*)(po + 8 * rq + 4 * hB)      = *(uint2*)pa.u;
            *(uint2*)(po + 32 + 8 * rq + 4 * hB) = *(uint2*)pb.u;
        }
    }
    if (hB == 0)
        PartL[(size_t)sp * N_ROWS + q0 + c] = lsum;
}

// -------------------------------------------------------------- merge ------
__global__ __launch_bounds__(256) void merge_kernel(
    const unsigned short* __restrict__ PartOb, const float* __restrict__ PartL,
    const float* __restrict__ Qf, float* __restrict__ out, int split)
{
    const int gid = blockIdx.x * 256 + threadIdx.x;   // 0 .. 8192*32-1
    const int q  = gid >> 5;
    const int dp = gid & 31;          // dv pair index

    float L = 0.f, a0 = 0.f, a1 = 0.f;
    for (int s = 0; s < split; ++s) {
        L += PartL[(size_t)s * N_ROWS + q];
        const unsigned v = *(const unsigned*)(PartOb + ((size_t)s * N_ROWS + q) * 64 + 2 * dp);
        a0 += bf2f((unsigned short)(v & 0xffffu));
        a1 += bf2f((unsigned short)(v >> 16));
    }
    const float invL = 1.f / L;
    const int d0 = 2 * dp;
    out[(size_t)q * 64 + d0]     = a0 * invL + Qf[(size_t)q * 64 + d0];
    out[(size_t)q * 64 + d0 + 1] = a1 * invL + Qf[(size_t)q * 64 + d0 + 1];
}

// ------------------------------------------------------------- launch ------
extern "C" void kernel_launch(void* const* d_in, const int* in_sizes, int n_in,
                              void* d_out, int out_size, void* d_ws, size_t ws_size,
                              hipStream_t stream)
{
    const float* x  = (const float*)d_in[0];
    const float* Wq = (const float*)d_in[1];
    const float* bq = (const float*)d_in[2];
    const float* Wk = (const float*)d_in[3];
    const float* bk = (const float*)d_in[4];
    const float* Wv = (const float*)d_in[5];
    const float* bv = (const float*)d_in[6];
    float* out = (float*)d_out;

    char* ws = (char*)d_ws;
    size_t off = 0;
    auto take = [&](size_t bytes) {
        char* p = ws + off;
        off += (bytes + 255) & ~(size_t)255;
        return p;
    };
    unsigned short* Qb = (unsigned short*)take((size_t)N_ROWS * DKV * 2);
    unsigned short* Kb = (unsigned short*)take((size_t)N_ROWS * DKV * 2);
    unsigned short* Vt = (unsigned short*)take((size_t)DKV * N_ROWS * 2);
    float*          Qf = (float*)take((size_t)N_ROWS * DKV * 4);

    int split = 16;
    const size_t per_split = (size_t)N_ROWS * 64 * 2 + (size_t)N_ROWS * 4 + 512;
    while (split > 1 && off + (size_t)split * per_split > ws_size) split >>= 1;

    unsigned short* PartOb = (unsigned short*)take((size_t)split * N_ROWS * 64 * 2);
    float*          PartL  = (float*)take((size_t)split * N_ROWS * 4);

    qkv_kernel<<<dim3(N_ROWS / 32), dim3(128), 0, stream>>>(
        x, Wq, bq, Wk, bk, Wv, bv, Qb, Kb, Vt, Qf);
    attn_kernel<<<dim3(N_ROWS / 256, split), dim3(512), 0, stream>>>(
        Qb, Kb, Vt, PartOb, PartL, N_ROWS / split);
    merge_kernel<<<dim3(N_ROWS * 32 / 256), dim3(256), 0, stream>>>(
        PartOb, PartL, Qf, out, split);
}